// Round 23
// baseline (5934.506 us; speedup 1.0000x reference)
//
#include <hip/hip_runtime.h>
#include <hip/hip_fp16.h>

#define BB 32
#define LL 512
#define HH 1024
#define NL 4
#define TPL 16   // tiles (blocks) per layer
#define CPB 64   // cols per block
#define TAGM 0x0001000100010001ULL   // LSB of each f16; per-f16 tags -> tear-proof
#define SROW 1032  // LDS row stride (f16)

typedef unsigned long long ull;
typedef unsigned short u16;
typedef _Float16 f16x8 __attribute__((ext_vector_type(8)));
typedef float    f32x4 __attribute__((ext_vector_type(4)));

__device__ __forceinline__ f16x8 cvt8(const float* __restrict__ p) {
  f32x4 lo = *reinterpret_cast<const f32x4*>(p);
  f32x4 hi = *reinterpret_cast<const f32x4*>(p + 4);
  f16x8 r;
#pragma unroll
  for (int e = 0; e < 4; ++e) { r[e] = (_Float16)lo[e]; r[e + 4] = (_Float16)hi[e]; }
  return r;
}

// Volatile weight load: the compiler may NOT re-execute a volatile load, so
// the converted f16 values must stay register-resident (defeats the
// rematerialize-from-L2 behavior suspected in rounds 18/20: VGPR_Count=128
// despite ~220 demand).
__device__ __forceinline__ f16x8 cvt8v(const float* p) {
  const volatile float* vp = (const volatile float*)p;
  float a[8];
#pragma unroll
  for (int e = 0; e < 8; ++e) a[e] = vp[e];
  f16x8 r;
#pragma unroll
  for (int e = 0; e < 8; ++e) r[e] = (_Float16)a[e];
  return r;
}

__device__ __forceinline__ ull tag_bad(f16x8 v, ull want) {
  union { f16x8 v; ull u[2]; } c; c.v = v;
  return ((c.u[0] ^ want) | (c.u[1] ^ want)) & TAGM;
}

// Guaranteed-terminating repair: 8B relaxed agent atomic (MALL) spin.
// Producer dual-stores the same address atomically (round-6-proven).
__device__ __forceinline__ f16x8 fix_q(const _Float16* __restrict__ gsrc, ull want) {
  const ull* p = reinterpret_cast<const ull*>(gsrc);
  union { ull u[2]; f16x8 v; } c;
  do {
    c.u[0] = __hip_atomic_load(p, __ATOMIC_RELAXED, __HIP_MEMORY_SCOPE_AGENT);
  } while ((c.u[0] ^ want) & TAGM);
  do {
    c.u[1] = __hip_atomic_load(p + 1, __ATOMIC_RELAXED, __HIP_MEMORY_SCOPE_AGENT);
  } while ((c.u[1] ^ want) & TAGM);
  return c.v;
}

// Persistent pipeline, 64 active blocks (grid 128): layer = blockIdx&7
// (XCD-locality heuristic only; tags + MALL retry keep correctness
// placement-free). Block: 64 cols, 256 threads, 4 waves; each wave owns
// 16 cols x FULL k=1024 x both matrices (256 weight VGPRs, volatile-pinned)
// -> NO cross-wave reduce, 2 barriers/step, epilogue via wave-private LDS
// transpose. Sync fabric = round-20 verbatim.
__global__ __launch_bounds__(256, 1) void rnn_persist(
    const float* __restrict__ x,   // [B][L][H] f32
    const float* __restrict__ h0,  // [NL][B][H] f32
    const float* __restrict__ WI,  // [NL][H][H] f32
    const float* __restrict__ BI,  // [NL][H]
    const float* __restrict__ WH,  // [NL][H][H] f32
    const float* __restrict__ BH,  // [NL][H]
    float* __restrict__ out,       // [B][L][H] f32 ++ hfinal [NL][B][H]
    _Float16* __restrict__ hbuf,   // [NL][RS][B][H] f16 (tagged)
    unsigned* __restrict__ pflag,  // [NL][TPL]: v => step v-1 complete
    int rsmask, int rshift) {
  const int l = blockIdx.x & 7;
  if (l >= NL) return;
  const int tile = blockIdx.x >> 3;   // 0..15
  const int c0   = tile * CPB;
  const int tid  = threadIdx.x;       // 0..255
  const int cg   = tid >> 6;          // wave 0..3 -> col group (16 cols)
  const int lane = tid & 63;
  const int crow = lane & 15;
  const int kgrp = lane >> 4;

  extern __shared__ char smem[];
  _Float16* sIn  = (_Float16*)smem;              // [32][SROW]
  _Float16* sHid = sIn + 32 * SROW;              // [32][SROW]
  u16*      sT   = (u16*)(sHid + 32 * SROW);     // [4 waves][32 rows][16 cols]

  // ---- weight fragments -> registers (once, volatile-pinned) ----
  // wave cg: cols c0+cg*16+crow, k = j*32 + kgrp*8, j=0..31, both matrices.
  f16x8 wIf[32], wHf[32];
  {
    const float* WIb = WI + (size_t)l * HH * HH + (size_t)(c0 + cg * 16 + crow) * HH;
    const float* WHb = WH + (size_t)l * HH * HH + (size_t)(c0 + cg * 16 + crow) * HH;
#pragma unroll
    for (int j = 0; j < 32; ++j) {
      const int k = j * 32 + kgrp * 8;
      wIf[j] = cvt8v(WIb + k);
      wHf[j] = cvt8v(WHb + k);
    }
  }

  const int mycol = c0 + cg * 16 + crow;   // this lane's single output column
  const float biasc = BI[l * HH + mycol] + BH[l * HH + mycol];

  for (int t = 0; t < LL; ++t) {
    const ull wantI = (((t >> rshift) & 1) ^ 1) ? TAGM : 0ULL;        // gen t
    const ull wantH = ((((t - 1) >> rshift) & 1) ^ 1) ? TAGM : 0ULL;  // gen t-1
    const u16 tgb   = (u16)((((t >> rshift) & 1) ^ 1) ? 1 : 0);

    // ---------- gates (round-20 verbatim semantics) ----------
    if (tid < 48) {
      if (tid < 16) {
        if (l > 0)
          while (__hip_atomic_load(&pflag[(l - 1) * TPL + tid], __ATOMIC_RELAXED,
                                   __HIP_MEMORY_SCOPE_AGENT) < (unsigned)(t + 1))
            __builtin_amdgcn_s_sleep(1);
      } else if (tid >= 32) {
        const int Lt = tid - 32;
        if (l < NL - 1 && t > rsmask)
          while (__hip_atomic_load(&pflag[(l + 1) * TPL + Lt], __ATOMIC_RELAXED,
                                   __HIP_MEMORY_SCOPE_AGENT) < (unsigned)(t - rsmask))
            __builtin_amdgcn_s_sleep(1);
      }
    }
    __syncthreads();   // barrier 1: gates passed + drains PREVIOUS step's stores
                       // + protects sIn/sHid against next-step overwrite

    // publish step t-1 completion (ordered by barrier-1's implicit drain)
    if (tid == 0 && t > 0)
      __hip_atomic_store(&pflag[l * TPL + tile], (unsigned)t, __ATOMIC_RELAXED,
                         __HIP_MEMORY_SCOPE_AGENT);

    const _Float16* srcI =
        hbuf + ((size_t)(l - 1) * (rsmask + 1) + (t & rsmask)) * BB * HH;
    const _Float16* srcH =
        hbuf + ((size_t)l * (rsmask + 1) + ((t - 1) & rsmask)) * BB * HH;

    // ---------- staging: 16 quanta/thread/operand. Issue I (MALL edge) first,
    // then H (local edge); settle H first (fast, local), then I. ----------
    f16x8 tqI[16], tqH[16];
    if (l == 0) {
#pragma unroll
      for (int it = 0; it < 16; ++it) {
        const int q = it * 256 + tid, row = q >> 7, col = (q & 127) * 8;
        tqI[it] = cvt8(x + ((size_t)row * LL + t) * HH + col);
      }
    } else {
#pragma unroll
      for (int it = 0; it < 16; ++it) {
        const int q = it * 256 + tid, row = q >> 7, col = (q & 127) * 8;
        tqI[it] = *reinterpret_cast<const f16x8*>(srcI + (size_t)row * HH + col);
      }
    }
    if (t == 0) {
#pragma unroll
      for (int it = 0; it < 16; ++it) {
        const int q = it * 256 + tid, row = q >> 7, col = (q & 127) * 8;
        tqH[it] = cvt8(h0 + ((size_t)l * BB + row) * HH + col);
      }
    } else {
#pragma unroll
      for (int it = 0; it < 16; ++it) {
        const int q = it * 256 + tid, row = q >> 7, col = (q & 127) * 8;
        tqH[it] = *reinterpret_cast<const f16x8*>(srcH + (size_t)row * HH + col);
      }
    }

    // settle hidden (critical path; tag-spin IS the sync)
    if (t != 0) {
      ull badH = 0;
#pragma unroll
      for (int it = 0; it < 16; ++it) badH |= tag_bad(tqH[it], wantH);
      if (badH) {
#pragma unroll
        for (int it = 0; it < 16; ++it) {
          const int q = it * 256 + tid, row = q >> 7, col = (q & 127) * 8;
          const _Float16* a = srcH + (size_t)row * HH + col;
          int tries = 0;
          while (tag_bad(tqH[it], wantH)) {
            if (tries++ < 64) {
              const volatile ull* vp = reinterpret_cast<const volatile ull*>(a);
              ull lo = vp[0], hi = vp[1];
              union { ull u[2]; f16x8 v; } c; c.u[0] = lo; c.u[1] = hi;
              tqH[it] = c.v;
            } else {
              tqH[it] = fix_q(a, wantH);
            }
          }
        }
      }
    }
#pragma unroll
    for (int it = 0; it < 16; ++it) {
      const int q = it * 256 + tid, row = q >> 7, col = (q & 127) * 8;
      *reinterpret_cast<f16x8*>(&sHid[(size_t)row * SROW + col]) = tqH[it];
    }

    // settle input (flag-gated: ~never retries)
    if (l != 0) {
      ull badI = 0;
#pragma unroll
      for (int it = 0; it < 16; ++it) badI |= tag_bad(tqI[it], wantI);
      if (badI) {
#pragma unroll
        for (int it = 0; it < 16; ++it) {
          const int q = it * 256 + tid, row = q >> 7, col = (q & 127) * 8;
          if (tag_bad(tqI[it], wantI))
            tqI[it] = fix_q(srcI + (size_t)row * HH + col, wantI);
        }
      }
    }
#pragma unroll
    for (int it = 0; it < 16; ++it) {
      const int q = it * 256 + tid, row = q >> 7, col = (q & 127) * 8;
      *reinterpret_cast<f16x8*>(&sIn[(size_t)row * SROW + col]) = tqI[it];
    }
    __syncthreads();   // barrier 2: LDS tiles complete

    // ---------- MFMA: full k per wave, both matrices, no reduce ----------
    f32x4 acc0 = {0.f, 0.f, 0.f, 0.f};   // rows 0..15
    f32x4 acc1 = {0.f, 0.f, 0.f, 0.f};   // rows 16..31
#pragma unroll
    for (int j = 0; j < 32; ++j) {
      const int base = j * 32 + kgrp * 8;
      f16x8 ai0 = *reinterpret_cast<const f16x8*>(&sIn [(size_t)crow * SROW + base]);
      f16x8 ai1 = *reinterpret_cast<const f16x8*>(&sIn [(size_t)(16 + crow) * SROW + base]);
      f16x8 ah0 = *reinterpret_cast<const f16x8*>(&sHid[(size_t)crow * SROW + base]);
      f16x8 ah1 = *reinterpret_cast<const f16x8*>(&sHid[(size_t)(16 + crow) * SROW + base]);
      acc0 = __builtin_amdgcn_mfma_f32_16x16x32_f16(ai0, wIf[j], acc0, 0, 0, 0);
      acc1 = __builtin_amdgcn_mfma_f32_16x16x32_f16(ai1, wIf[j], acc1, 0, 0, 0);
      acc0 = __builtin_amdgcn_mfma_f32_16x16x32_f16(ah0, wHf[j], acc0, 0, 0, 0);
      acc1 = __builtin_amdgcn_mfma_f32_16x16x32_f16(ah1, wHf[j], acc1, 0, 0, 0);
    }

    // ---------- epilogue: tanh in regs -> tagged f16 -> wave-private LDS
    // transpose (no block barrier; intra-wave lgkmcnt ordering) ----------
    u16* sTw = sT + cg * 512;   // [32 rows][16 cols]
#pragma unroll
    for (int r = 0; r < 4; ++r) {
      const float v0 = tanhf(acc0[r] + biasc);
      const float v1 = tanhf(acc1[r] + biasc);
      _Float16 h0v = (_Float16)v0, h1v = (_Float16)v1;
      u16 u0, u1;
      __builtin_memcpy(&u0, &h0v, 2);
      __builtin_memcpy(&u1, &h1v, 2);
      u0 = (u16)((u0 & 0xFFFEu) | tgb);
      u1 = (u16)((u1 & 0xFFFEu) | tgb);
      sTw[(kgrp * 4 + r) * 16 + crow]      = u0;
      sTw[(16 + kgrp * 4 + r) * 16 + crow] = u1;
    }
    __builtin_amdgcn_wave_barrier();   // keep write->read order within wave

    const int rowq = lane >> 1;               // 0..31
    const int c8   = (lane & 1) * 8;          // 0 or 8 (f16 units)
    f16x8 hq = *reinterpret_cast<const f16x8*>(&sTw[rowq * 16 + c8]);

    {
      const size_t off = ((size_t)l * (rsmask + 1) + (t & rsmask)) * BB * HH +
                         (size_t)rowq * HH + c0 + cg * 16 + c8;
      // dual store, SAME address (round-15/20-proven): plain 16B (dirty local
      // L2; per-f16 tags make any tearing safe) + 2x8B atomic write-through
      // (MALL master / termination guarantee)
      *reinterpret_cast<f16x8*>(hbuf + off) = hq;
      union { f16x8 v; ull u[2]; } cc; cc.v = hq;
      __hip_atomic_store(reinterpret_cast<ull*>(hbuf + off), cc.u[0],
                         __ATOMIC_RELAXED, __HIP_MEMORY_SCOPE_AGENT);
      __hip_atomic_store(reinterpret_cast<ull*>(hbuf + off) + 1, cc.u[1],
                         __ATOMIC_RELAXED, __HIP_MEMORY_SCOPE_AGENT);

      if (l == NL - 1) {
        f32x4 o0, o1;
#pragma unroll
        for (int e = 0; e < 4; ++e) { o0[e] = (float)hq[e]; o1[e] = (float)hq[e + 4]; }
        float* po = out + ((size_t)rowq * LL + t) * HH + c0 + cg * 16 + c8;
        __builtin_nontemporal_store(o0, reinterpret_cast<f32x4*>(po));
        __builtin_nontemporal_store(o1, reinterpret_cast<f32x4*>(po + 4));
      }
      if (t == LL - 1) {
        f32x4 o0, o1;
#pragma unroll
        for (int e = 0; e < 4; ++e) { o0[e] = (float)hq[e]; o1[e] = (float)hq[e + 4]; }
        float* pf = out + (size_t)BB * LL * HH +
                    ((size_t)l * BB + rowq) * HH + c0 + cg * 16 + c8;
        __builtin_nontemporal_store(o0, reinterpret_cast<f32x4*>(pf));
        __builtin_nontemporal_store(o1, reinterpret_cast<f32x4*>(pf + 4));
      }
    }
  }

  // final publish: step LL-1 complete (ordered after drain)
  __syncthreads();
  if (tid == 0)
    __hip_atomic_store(&pflag[l * TPL + tile], (unsigned)LL, __ATOMIC_RELAXED,
                       __HIP_MEMORY_SCOPE_AGENT);
}

extern "C" void kernel_launch(void* const* d_in, const int* in_sizes, int n_in,
                              void* d_out, int out_size, void* d_ws, size_t ws_size,
                              hipStream_t stream) {
  const float* x  = (const float*)d_in[0];
  const float* h0 = (const float*)d_in[1];
  const float* WI = (const float*)d_in[2];
  const float* BI = (const float*)d_in[3];
  const float* WH = (const float*)d_in[4];
  const float* BH = (const float*)d_in[5];
  float* out = (float*)d_out;

  // RS (slots per layer): prefer 512 = fully write-once h stream (no WAR).
  const size_t perSlot = (size_t)NL * BB * HH * sizeof(_Float16);  // 256 KB
  int rs = 512;
  while (rs > 8 && (size_t)rs * perSlot + 65536 > ws_size) rs >>= 1;
  int rshift = 0;
  while ((1 << rshift) < rs) ++rshift;

  _Float16* hbuf = (_Float16*)d_ws;
  unsigned* pflag = (unsigned*)((char*)d_ws + (size_t)rs * perSlot);

  const int smemBytes = 2 * 32 * SROW * (int)sizeof(_Float16) +
                        4 * 512 * (int)sizeof(u16);   // 132096 + 4096 = 136192
  static int attrSet = 0;
  if (!attrSet) {
    hipFuncSetAttribute(reinterpret_cast<const void*>(rnn_persist),
                        hipFuncAttributeMaxDynamicSharedMemorySize, smemBytes);
    attrSet = 1;
  }

  hipMemsetAsync(pflag, 0, (size_t)NL * TPL * sizeof(unsigned), stream);
  rnn_persist<<<128, 256, smemBytes, stream>>>(x, h0, WI, BI, WH, BH, out, hbuf,
                                               pflag, rs - 1, rshift);
}

// Round 24
// 3432.209 us; speedup vs baseline: 1.7291x; 1.7291x over previous
//
#include <hip/hip_runtime.h>
#include <hip/hip_fp16.h>

#define BB 32
#define LL 512
#define HH 1024
#define NL 4
#define TPL 16   // tiles (blocks) per layer
#define CPB 64   // cols per block
#define TAGM 0x0001000100010001ULL   // LSB of each f16; per-f16 tags -> tear-proof
#define SROW 1032  // LDS row stride (f16)

typedef unsigned long long ull;
typedef _Float16 f16x8 __attribute__((ext_vector_type(8)));
typedef float    f32x4 __attribute__((ext_vector_type(4)));

__device__ __forceinline__ f16x8 cvt8(const float* __restrict__ p) {
  f32x4 lo = *reinterpret_cast<const f32x4*>(p);
  f32x4 hi = *reinterpret_cast<const f32x4*>(p + 4);
  f16x8 r;
#pragma unroll
  for (int e = 0; e < 4; ++e) { r[e] = (_Float16)lo[e]; r[e + 4] = (_Float16)hi[e]; }
  return r;
}

// Volatile weight load: compiler may not re-execute a volatile load, so the
// converted f16 fragments must stay resident in the register file (VGPR or
// AGPR overflow) instead of being rematerialized from L2 every K-loop — the
// round-20 allocator chose remat (VGPR_Count=128 vs ~244 demand).
__device__ __forceinline__ f16x8 cvt8v(const float* p) {
  const volatile float* vp = (const volatile float*)p;
  float a[8];
#pragma unroll
  for (int e = 0; e < 8; ++e) a[e] = vp[e];
  f16x8 r;
#pragma unroll
  for (int e = 0; e < 8; ++e) r[e] = (_Float16)a[e];
  return r;
}

__device__ __forceinline__ ull tag_bad(f16x8 v, ull want) {
  union { f16x8 v; ull u[2]; } c; c.v = v;
  return ((c.u[0] ^ want) | (c.u[1] ^ want)) & TAGM;
}

// Guaranteed-terminating repair: 8B relaxed agent atomic (MALL) spin.
// Producer dual-stores the same address atomically (round-6-proven).
__device__ __forceinline__ f16x8 fix_q(const _Float16* __restrict__ gsrc, ull want) {
  const ull* p = reinterpret_cast<const ull*>(gsrc);
  union { ull u[2]; f16x8 v; } c;
  do {
    c.u[0] = __hip_atomic_load(p, __ATOMIC_RELAXED, __HIP_MEMORY_SCOPE_AGENT);
  } while ((c.u[0] ^ want) & TAGM);
  do {
    c.u[1] = __hip_atomic_load(p + 1, __ATOMIC_RELAXED, __HIP_MEMORY_SCOPE_AGENT);
  } while ((c.u[1] ^ want) & TAGM);
  return c.v;
}

// Persistent pipeline, 64 active blocks (grid 128): layer = blockIdx&7
// (XCD-locality heuristic only; tags + MALL retry keep correctness
// placement-free). Block: 64 cols, 512 threads, 8 waves (wave = k-eighth),
// weights VOLATILE-pinned in registers (128 VGPR; total demand ~244 <= 256
// per-wave cap at 2 waves/SIMD). Otherwise round-20 optimum verbatim.
__global__ __launch_bounds__(512, 1) void rnn_persist(
    const float* __restrict__ x,   // [B][L][H] f32
    const float* __restrict__ h0,  // [NL][B][H] f32
    const float* __restrict__ WI,  // [NL][H][H] f32
    const float* __restrict__ BI,  // [NL][H]
    const float* __restrict__ WH,  // [NL][H][H] f32
    const float* __restrict__ BH,  // [NL][H]
    float* __restrict__ out,       // [B][L][H] f32 ++ hfinal [NL][B][H]
    _Float16* __restrict__ hbuf,   // [NL][RS][B][H] f16 (tagged)
    unsigned* __restrict__ pflag,  // [NL][TPL]: v => step v-1 complete
    int rsmask, int rshift) {
  const int l = blockIdx.x & 7;
  if (l >= NL) return;
  const int tile = blockIdx.x >> 3;   // 0..15
  const int c0   = tile * CPB;
  const int tid  = threadIdx.x;       // 0..511
  const int w    = tid >> 6;          // wave 0..7 -> k-eighth [w*128, w*128+128)
  const int lane = tid & 63;
  const int crow = lane & 15;
  const int kgrp = lane >> 4;

  extern __shared__ char smem[];
  _Float16* sIn  = (_Float16*)smem;            // [32][SROW]
  _Float16* sHid = sIn + 32 * SROW;            // [32][SROW]
  float*    redp = (float*)smem;               // [8][32][68] ALIASED over staging
#define RED(W2, R, C) redp[(((W2) * 32 + (R)) * 68) + (C)]

  // ---- weight fragments -> registers (once, VOLATILE-pinned) ----
  f16x8 wIf[4][4], wHf[4][4];
  {
    const float* WIb = WI + (size_t)l * HH * HH;
    const float* WHb = WH + (size_t)l * HH * HH;
#pragma unroll
    for (int ct = 0; ct < 4; ++ct) {
      const size_t row = (size_t)(c0 + ct * 16 + crow) * HH;
#pragma unroll
      for (int j = 0; j < 4; ++j) {
        const int k = w * 128 + kgrp * 8 + j * 32;
        wIf[ct][j] = cvt8v(WIb + row + k);
        wHf[ct][j] = cvt8v(WHb + row + k);
      }
    }
  }

  // staging: q = it*512+tid -> row=q>>7, col=(q&127)*8 (8 quanta/thread/operand)
  // epilogue: thread -> (row rb, 4 cols at c4) = one 8B tagged quantum
  const int rb = tid >> 4;          // 0..31
  const int c4 = (tid & 15) * 4;    // 0..60
  float bias4[4];
#pragma unroll
  for (int j = 0; j < 4; ++j)
    bias4[j] = BI[l * HH + c0 + c4 + j] + BH[l * HH + c0 + c4 + j];

  for (int t = 0; t < LL; ++t) {
    const ull wantI = (((t >> rshift) & 1) ^ 1) ? TAGM : 0ULL;        // gen t
    const ull wantH = ((((t - 1) >> rshift) & 1) ^ 1) ? TAGM : 0ULL;  // gen t-1

    // ---------- gates (round-15/18/20 order, verbatim semantics) ----------
    if (tid < 48) {
      if (tid < 16) {
        if (l > 0)
          while (__hip_atomic_load(&pflag[(l - 1) * TPL + tid], __ATOMIC_RELAXED,
                                   __HIP_MEMORY_SCOPE_AGENT) < (unsigned)(t + 1))
            __builtin_amdgcn_s_sleep(1);
      } else if (tid >= 32) {
        const int Lt = tid - 32;
        if (l < NL - 1 && t > rsmask)
          while (__hip_atomic_load(&pflag[(l + 1) * TPL + Lt], __ATOMIC_RELAXED,
                                   __HIP_MEMORY_SCOPE_AGENT) < (unsigned)(t - rsmask))
            __builtin_amdgcn_s_sleep(1);
      }
    }
    __syncthreads();   // barrier 1: gates passed + drains PREVIOUS step's stores

    // publish step t-1 completion (ordered by barrier-1's implicit drain)
    if (tid == 0 && t > 0)
      __hip_atomic_store(&pflag[l * TPL + tile], (unsigned)t, __ATOMIC_RELAXED,
                         __HIP_MEMORY_SCOPE_AGENT);

    const _Float16* srcI =
        hbuf + ((size_t)(l - 1) * (rsmask + 1) + (t & rsmask)) * BB * HH;
    const _Float16* srcH =
        hbuf + ((size_t)l * (rsmask + 1) + ((t - 1) & rsmask)) * BB * HH;

    // ---------- phase I: input operand -> regs -> settle -> LDS ----------
    {
      f16x8 tq[8];
      if (l == 0) {
#pragma unroll
        for (int it = 0; it < 8; ++it) {
          const int q = it * 512 + tid, row = q >> 7, col = (q & 127) * 8;
          tq[it] = cvt8(x + ((size_t)row * LL + t) * HH + col);
        }
      } else {
#pragma unroll
        for (int it = 0; it < 8; ++it) {
          const int q = it * 512 + tid, row = q >> 7, col = (q & 127) * 8;
          tq[it] = *reinterpret_cast<const f16x8*>(srcI + (size_t)row * HH + col);
        }
        ull badI = 0;
#pragma unroll
        for (int it = 0; it < 8; ++it) badI |= tag_bad(tq[it], wantI);
        if (badI) {
#pragma unroll
          for (int it = 0; it < 8; ++it) {
            const int q = it * 512 + tid, row = q >> 7, col = (q & 127) * 8;
            if (tag_bad(tq[it], wantI))
              tq[it] = fix_q(srcI + (size_t)row * HH + col, wantI);
          }
        }
      }
#pragma unroll
      for (int it = 0; it < 8; ++it) {
        const int q = it * 512 + tid, row = q >> 7, col = (q & 127) * 8;
        *reinterpret_cast<f16x8*>(&sIn[(size_t)row * SROW + col]) = tq[it];
      }
    }

    // ---------- phase H: hidden operand -> regs -> settle -> LDS ----------
    {
      f16x8 tq[8];
      if (t == 0) {
#pragma unroll
        for (int it = 0; it < 8; ++it) {
          const int q = it * 512 + tid, row = q >> 7, col = (q & 127) * 8;
          tq[it] = cvt8(h0 + ((size_t)l * BB + row) * HH + col);
        }
      } else {
#pragma unroll
        for (int it = 0; it < 8; ++it) {
          const int q = it * 512 + tid, row = q >> 7, col = (q & 127) * 8;
          tq[it] = *reinterpret_cast<const f16x8*>(srcH + (size_t)row * HH + col);
        }
        ull badH = 0;
#pragma unroll
        for (int it = 0; it < 8; ++it) badH |= tag_bad(tq[it], wantH);
        if (badH) {   // round-15 settle: volatile tier (same-XCD L2), then MALL
#pragma unroll
          for (int it = 0; it < 8; ++it) {
            const int q = it * 512 + tid, row = q >> 7, col = (q & 127) * 8;
            const _Float16* a = srcH + (size_t)row * HH + col;
            int tries = 0;
            while (tag_bad(tq[it], wantH)) {
              if (tries++ < 64) {
                const volatile ull* vp = reinterpret_cast<const volatile ull*>(a);
                ull lo = vp[0], hi = vp[1];
                union { ull u[2]; f16x8 v; } c; c.u[0] = lo; c.u[1] = hi;
                tq[it] = c.v;
              } else {
                tq[it] = fix_q(a, wantH);
              }
            }
          }
        }
      }
#pragma unroll
      for (int it = 0; it < 8; ++it) {
        const int q = it * 512 + tid, row = q >> 7, col = (q & 127) * 8;
        *reinterpret_cast<f16x8*>(&sHid[(size_t)row * SROW + col]) = tq[it];
      }
    }
    __syncthreads();   // barrier 2: LDS tiles complete

    // ---------- MFMA from LDS (wave = k-eighth, 4 col-subtiles) ----------
    f32x4 acc[4][2];
#pragma unroll
    for (int ct = 0; ct < 4; ++ct)
#pragma unroll
      for (int rt = 0; rt < 2; ++rt) acc[ct][rt] = (f32x4){0.f, 0.f, 0.f, 0.f};
#pragma unroll
    for (int j = 0; j < 4; ++j) {
      const int base = w * 128 + kgrp * 8 + j * 32;
      f16x8 ai0 = *reinterpret_cast<const f16x8*>(&sIn [(size_t)crow * SROW + base]);
      f16x8 ai1 = *reinterpret_cast<const f16x8*>(&sIn [(size_t)(16 + crow) * SROW + base]);
      f16x8 ah0 = *reinterpret_cast<const f16x8*>(&sHid[(size_t)crow * SROW + base]);
      f16x8 ah1 = *reinterpret_cast<const f16x8*>(&sHid[(size_t)(16 + crow) * SROW + base]);
#pragma unroll
      for (int ct = 0; ct < 4; ++ct) {
        acc[ct][0] = __builtin_amdgcn_mfma_f32_16x16x32_f16(ai0, wIf[ct][j], acc[ct][0], 0, 0, 0);
        acc[ct][1] = __builtin_amdgcn_mfma_f32_16x16x32_f16(ai1, wIf[ct][j], acc[ct][1], 0, 0, 0);
        acc[ct][0] = __builtin_amdgcn_mfma_f32_16x16x32_f16(ah0, wHf[ct][j], acc[ct][0], 0, 0, 0);
        acc[ct][1] = __builtin_amdgcn_mfma_f32_16x16x32_f16(ah1, wHf[ct][j], acc[ct][1], 0, 0, 0);
      }
    }
    __syncthreads();   // barrier 3: all LDS reads done (red aliases staging)

    // ---------- cross-wave k-reduce: write partials ----------
#pragma unroll
    for (int ct = 0; ct < 4; ++ct)
#pragma unroll
      for (int rt = 0; rt < 2; ++rt)
#pragma unroll
        for (int r = 0; r < 4; ++r)
          RED(w, rt * 16 + kgrp * 4 + r, ct * 16 + crow) = acc[ct][rt][r];
    __syncthreads();   // barrier 4: partials complete

    // ---------- epilogue: all 512 threads, 4 cols each ----------
    float v[4];
#pragma unroll
    for (int j = 0; j < 4; ++j) {
      float s = bias4[j];
#pragma unroll
      for (int w2 = 0; w2 < 8; ++w2) s += RED(w2, rb, c4 + j);
      v[j] = tanhf(s);
    }
    {
      union { _Float16 h[4]; ull u; } pk;
#pragma unroll
      for (int j = 0; j < 4; ++j) pk.h[j] = (_Float16)v[j];
      const ull tg = (((t >> rshift) & 1) ^ 1) ? TAGM : 0ULL;
      pk.u = (pk.u & ~TAGM) | tg;
      const size_t off =
          ((size_t)l * (rsmask + 1) + (t & rsmask)) * BB * HH + (size_t)rb * HH + c0 + c4;
      // dual store, SAME address (round-15/20-proven): plain (dirty local L2)
      // + atomic write-through (MALL master / termination guarantee)
      *reinterpret_cast<ull*>(hbuf + off) = pk.u;
      __hip_atomic_store(reinterpret_cast<ull*>(hbuf + off), pk.u,
                         __ATOMIC_RELAXED, __HIP_MEMORY_SCOPE_AGENT);
    }
    if (l == NL - 1) {
      f32x4 o = {v[0], v[1], v[2], v[3]};
      __builtin_nontemporal_store(
          o, reinterpret_cast<f32x4*>(out + ((size_t)rb * LL + t) * HH + c0 + c4));
    }
    if (t == LL - 1) {
      f32x4 o = {v[0], v[1], v[2], v[3]};
      __builtin_nontemporal_store(
          o, reinterpret_cast<f32x4*>(out + (size_t)BB * LL * HH +
                                      ((size_t)l * BB + rb) * HH + c0 + c4));
    }
  }

  // final publish: step LL-1 complete (ordered after drain)
  __syncthreads();
  if (tid == 0)
    __hip_atomic_store(&pflag[l * TPL + tile], (unsigned)LL, __ATOMIC_RELAXED,
                       __HIP_MEMORY_SCOPE_AGENT);
#undef RED
}

extern "C" void kernel_launch(void* const* d_in, const int* in_sizes, int n_in,
                              void* d_out, int out_size, void* d_ws, size_t ws_size,
                              hipStream_t stream) {
  const float* x  = (const float*)d_in[0];
  const float* h0 = (const float*)d_in[1];
  const float* WI = (const float*)d_in[2];
  const float* BI = (const float*)d_in[3];
  const float* WH = (const float*)d_in[4];
  const float* BH = (const float*)d_in[5];
  float* out = (float*)d_out;

  // RS (slots per layer): prefer 512 = fully write-once h stream (no WAR).
  const size_t perSlot = (size_t)NL * BB * HH * sizeof(_Float16);  // 256 KB
  int rs = 512;
  while (rs > 8 && (size_t)rs * perSlot + 65536 > ws_size) rs >>= 1;
  int rshift = 0;
  while ((1 << rshift) < rs) ++rshift;

  _Float16* hbuf = (_Float16*)d_ws;
  unsigned* pflag = (unsigned*)((char*)d_ws + (size_t)rs * perSlot);

  const int smemBytes = 2 * 32 * SROW * (int)sizeof(_Float16);  // 132096 (red aliased)
  static int attrSet = 0;
  if (!attrSet) {
    hipFuncSetAttribute(reinterpret_cast<const void*>(rnn_persist),
                        hipFuncAttributeMaxDynamicSharedMemorySize, smemBytes);
    attrSet = 1;
  }

  hipMemsetAsync(pflag, 0, (size_t)NL * TPL * sizeof(unsigned), stream);
  rnn_persist<<<128, 512, smemBytes, stream>>>(x, h0, WI, BI, WH, BH, out, hbuf,
                                               pflag, rs - 1, rshift);
}

// Round 25
// 3418.981 us; speedup vs baseline: 1.7358x; 1.0039x over previous
//
#include <hip/hip_runtime.h>
#include <hip/hip_fp16.h>

#define BB 32
#define LL 512
#define HH 1024
#define NL 4
#define TPL 16   // tiles (blocks) per layer
#define CPB 64   // cols per block
#define TAGM 0x0001000100010001ULL   // LSB of each f16; per-f16 tags -> tear-proof
#define SROW 1032  // LDS row stride (f16)

typedef unsigned long long ull;
typedef _Float16 f16x8 __attribute__((ext_vector_type(8)));
typedef float    f32x4 __attribute__((ext_vector_type(4)));

__device__ __forceinline__ f16x8 cvt8(const float* __restrict__ p) {
  f32x4 lo = *reinterpret_cast<const f32x4*>(p);
  f32x4 hi = *reinterpret_cast<const f32x4*>(p + 4);
  f16x8 r;
#pragma unroll
  for (int e = 0; e < 4; ++e) { r[e] = (_Float16)lo[e]; r[e + 4] = (_Float16)hi[e]; }
  return r;
}

// Volatile weight load (round-24 base): compiler may not re-execute it.
__device__ __forceinline__ f16x8 cvt8v(const float* p) {
  const volatile float* vp = (const volatile float*)p;
  float a[8];
#pragma unroll
  for (int e = 0; e < 8; ++e) a[e] = vp[e];
  f16x8 r;
#pragma unroll
  for (int e = 0; e < 8; ++e) r[e] = (_Float16)a[e];
  return r;
}

__device__ __forceinline__ ull tag_bad(f16x8 v, ull want) {
  union { f16x8 v; ull u[2]; } c; c.v = v;
  return ((c.u[0] ^ want) | (c.u[1] ^ want)) & TAGM;
}

// Guaranteed-terminating repair: 8B relaxed agent atomic (MALL) spin.
// Producer dual-stores the same address atomically (round-6-proven).
__device__ __forceinline__ f16x8 fix_q(const _Float16* __restrict__ gsrc, ull want) {
  const ull* p = reinterpret_cast<const ull*>(gsrc);
  union { ull u[2]; f16x8 v; } c;
  do {
    c.u[0] = __hip_atomic_load(p, __ATOMIC_RELAXED, __HIP_MEMORY_SCOPE_AGENT);
  } while ((c.u[0] ^ want) & TAGM);
  do {
    c.u[1] = __hip_atomic_load(p + 1, __ATOMIC_RELAXED, __HIP_MEMORY_SCOPE_AGENT);
  } while ((c.u[1] ^ want) & TAGM);
  return c.v;
}

// Persistent pipeline, 64 active blocks (grid 128): layer = blockIdx&7
// (XCD-locality heuristic only; tags + MALL retry keep correctness
// placement-free). Round-24 base + DRAIN-EARLY: an explicit barrier right
// after the h/out stores (forces vmcnt(0) -> h visible in L2/MALL at END of
// step t, not at the producers' next barrier-1) and the publish immediately
// after it (un-chains the cross-layer publish convoy; strictest ordering).
__global__ __launch_bounds__(512, 1) void rnn_persist(
    const float* __restrict__ x,   // [B][L][H] f32
    const float* __restrict__ h0,  // [NL][B][H] f32
    const float* __restrict__ WI,  // [NL][H][H] f32
    const float* __restrict__ BI,  // [NL][H]
    const float* __restrict__ WH,  // [NL][H][H] f32
    const float* __restrict__ BH,  // [NL][H]
    float* __restrict__ out,       // [B][L][H] f32 ++ hfinal [NL][B][H]
    _Float16* __restrict__ hbuf,   // [NL][RS][B][H] f16 (tagged)
    unsigned* __restrict__ pflag,  // [NL][TPL]: v => step v-1 complete+drained
    int rsmask, int rshift) {
  const int l = blockIdx.x & 7;
  if (l >= NL) return;
  const int tile = blockIdx.x >> 3;   // 0..15
  const int c0   = tile * CPB;
  const int tid  = threadIdx.x;       // 0..511
  const int w    = tid >> 6;          // wave 0..7 -> k-eighth [w*128, w*128+128)
  const int lane = tid & 63;
  const int crow = lane & 15;
  const int kgrp = lane >> 4;

  extern __shared__ char smem[];
  _Float16* sIn  = (_Float16*)smem;            // [32][SROW]
  _Float16* sHid = sIn + 32 * SROW;            // [32][SROW]
  float*    redp = (float*)smem;               // [8][32][68] ALIASED over staging
#define RED(W2, R, C) redp[(((W2) * 32 + (R)) * 68) + (C)]

  // ---- weight fragments -> registers (once, volatile-pinned) ----
  f16x8 wIf[4][4], wHf[4][4];
  {
    const float* WIb = WI + (size_t)l * HH * HH;
    const float* WHb = WH + (size_t)l * HH * HH;
#pragma unroll
    for (int ct = 0; ct < 4; ++ct) {
      const size_t row = (size_t)(c0 + ct * 16 + crow) * HH;
#pragma unroll
      for (int j = 0; j < 4; ++j) {
        const int k = w * 128 + kgrp * 8 + j * 32;
        wIf[ct][j] = cvt8v(WIb + row + k);
        wHf[ct][j] = cvt8v(WHb + row + k);
      }
    }
  }

  // staging: q = it*512+tid -> row=q>>7, col=(q&127)*8 (8 quanta/thread/operand)
  // epilogue: thread -> (row rb, 4 cols at c4) = one 8B tagged quantum
  const int rb = tid >> 4;          // 0..31
  const int c4 = (tid & 15) * 4;    // 0..60
  float bias4[4];
#pragma unroll
  for (int j = 0; j < 4; ++j)
    bias4[j] = BI[l * HH + c0 + c4 + j] + BH[l * HH + c0 + c4 + j];

  for (int t = 0; t < LL; ++t) {
    const ull wantI = (((t >> rshift) & 1) ^ 1) ? TAGM : 0ULL;        // gen t
    const ull wantH = ((((t - 1) >> rshift) & 1) ^ 1) ? TAGM : 0ULL;  // gen t-1

    // ---------- gates (round-20 semantics; publish is now immediate so these
    // are satisfied earlier) ----------
    if (tid < 48) {
      if (tid < 16) {
        if (l > 0)
          while (__hip_atomic_load(&pflag[(l - 1) * TPL + tid], __ATOMIC_RELAXED,
                                   __HIP_MEMORY_SCOPE_AGENT) < (unsigned)(t + 1))
            __builtin_amdgcn_s_sleep(1);
      } else if (tid >= 32) {
        const int Lt = tid - 32;
        if (l < NL - 1 && t > rsmask)
          while (__hip_atomic_load(&pflag[(l + 1) * TPL + Lt], __ATOMIC_RELAXED,
                                   __HIP_MEMORY_SCOPE_AGENT) < (unsigned)(t - rsmask))
            __builtin_amdgcn_s_sleep(1);
      }
    }
    __syncthreads();   // barrier 1: gates passed

    const _Float16* srcI =
        hbuf + ((size_t)(l - 1) * (rsmask + 1) + (t & rsmask)) * BB * HH;
    const _Float16* srcH =
        hbuf + ((size_t)l * (rsmask + 1) + ((t - 1) & rsmask)) * BB * HH;

    // ---------- phase I: input operand -> regs -> settle -> LDS ----------
    {
      f16x8 tq[8];
      if (l == 0) {
#pragma unroll
        for (int it = 0; it < 8; ++it) {
          const int q = it * 512 + tid, row = q >> 7, col = (q & 127) * 8;
          tq[it] = cvt8(x + ((size_t)row * LL + t) * HH + col);
        }
      } else {
#pragma unroll
        for (int it = 0; it < 8; ++it) {
          const int q = it * 512 + tid, row = q >> 7, col = (q & 127) * 8;
          tq[it] = *reinterpret_cast<const f16x8*>(srcI + (size_t)row * HH + col);
        }
        ull badI = 0;
#pragma unroll
        for (int it = 0; it < 8; ++it) badI |= tag_bad(tq[it], wantI);
        if (badI) {
#pragma unroll
          for (int it = 0; it < 8; ++it) {
            const int q = it * 512 + tid, row = q >> 7, col = (q & 127) * 8;
            if (tag_bad(tq[it], wantI))
              tq[it] = fix_q(srcI + (size_t)row * HH + col, wantI);
          }
        }
      }
#pragma unroll
      for (int it = 0; it < 8; ++it) {
        const int q = it * 512 + tid, row = q >> 7, col = (q & 127) * 8;
        *reinterpret_cast<f16x8*>(&sIn[(size_t)row * SROW + col]) = tq[it];
      }
    }

    // ---------- phase H: hidden operand -> regs -> settle -> LDS ----------
    {
      f16x8 tq[8];
      if (t == 0) {
#pragma unroll
        for (int it = 0; it < 8; ++it) {
          const int q = it * 512 + tid, row = q >> 7, col = (q & 127) * 8;
          tq[it] = cvt8(h0 + ((size_t)l * BB + row) * HH + col);
        }
      } else {
#pragma unroll
        for (int it = 0; it < 8; ++it) {
          const int q = it * 512 + tid, row = q >> 7, col = (q & 127) * 8;
          tq[it] = *reinterpret_cast<const f16x8*>(srcH + (size_t)row * HH + col);
        }
        ull badH = 0;
#pragma unroll
        for (int it = 0; it < 8; ++it) badH |= tag_bad(tq[it], wantH);
        if (badH) {   // settle: volatile tier (same-XCD L2), then MALL net
#pragma unroll
          for (int it = 0; it < 8; ++it) {
            const int q = it * 512 + tid, row = q >> 7, col = (q & 127) * 8;
            const _Float16* a = srcH + (size_t)row * HH + col;
            int tries = 0;
            while (tag_bad(tq[it], wantH)) {
              if (tries++ < 64) {
                const volatile ull* vp = reinterpret_cast<const volatile ull*>(a);
                ull lo = vp[0], hi = vp[1];
                union { ull u[2]; f16x8 v; } c; c.u[0] = lo; c.u[1] = hi;
                tq[it] = c.v;
              } else {
                tq[it] = fix_q(a, wantH);
              }
            }
          }
        }
      }
#pragma unroll
      for (int it = 0; it < 8; ++it) {
        const int q = it * 512 + tid, row = q >> 7, col = (q & 127) * 8;
        *reinterpret_cast<f16x8*>(&sHid[(size_t)row * SROW + col]) = tq[it];
      }
    }
    __syncthreads();   // barrier 2: LDS tiles complete

    // ---------- MFMA from LDS (wave = k-eighth, 4 col-subtiles) ----------
    f32x4 acc[4][2];
#pragma unroll
    for (int ct = 0; ct < 4; ++ct)
#pragma unroll
      for (int rt = 0; rt < 2; ++rt) acc[ct][rt] = (f32x4){0.f, 0.f, 0.f, 0.f};
#pragma unroll
    for (int j = 0; j < 4; ++j) {
      const int base = w * 128 + kgrp * 8 + j * 32;
      f16x8 ai0 = *reinterpret_cast<const f16x8*>(&sIn [(size_t)crow * SROW + base]);
      f16x8 ai1 = *reinterpret_cast<const f16x8*>(&sIn [(size_t)(16 + crow) * SROW + base]);
      f16x8 ah0 = *reinterpret_cast<const f16x8*>(&sHid[(size_t)crow * SROW + base]);
      f16x8 ah1 = *reinterpret_cast<const f16x8*>(&sHid[(size_t)(16 + crow) * SROW + base]);
#pragma unroll
      for (int ct = 0; ct < 4; ++ct) {
        acc[ct][0] = __builtin_amdgcn_mfma_f32_16x16x32_f16(ai0, wIf[ct][j], acc[ct][0], 0, 0, 0);
        acc[ct][1] = __builtin_amdgcn_mfma_f32_16x16x32_f16(ai1, wIf[ct][j], acc[ct][1], 0, 0, 0);
        acc[ct][0] = __builtin_amdgcn_mfma_f32_16x16x32_f16(ah0, wHf[ct][j], acc[ct][0], 0, 0, 0);
        acc[ct][1] = __builtin_amdgcn_mfma_f32_16x16x32_f16(ah1, wHf[ct][j], acc[ct][1], 0, 0, 0);
      }
    }
    __syncthreads();   // barrier 3: all LDS reads done (RED aliases staging)

    // ---------- cross-wave k-reduce: write partials ----------
#pragma unroll
    for (int ct = 0; ct < 4; ++ct)
#pragma unroll
      for (int rt = 0; rt < 2; ++rt)
#pragma unroll
        for (int r = 0; r < 4; ++r)
          RED(w, rt * 16 + kgrp * 4 + r, ct * 16 + crow) = acc[ct][rt][r];
    __syncthreads();   // barrier 4: partials complete

    // ---------- epilogue: all 512 threads, 4 cols each ----------
    float v[4];
#pragma unroll
    for (int j = 0; j < 4; ++j) {
      float s = bias4[j];
#pragma unroll
      for (int w2 = 0; w2 < 8; ++w2) s += RED(w2, rb, c4 + j);
      v[j] = tanhf(s);
    }
    {
      union { _Float16 h[4]; ull u; } pk;
#pragma unroll
      for (int j = 0; j < 4; ++j) pk.h[j] = (_Float16)v[j];
      const ull tg = (((t >> rshift) & 1) ^ 1) ? TAGM : 0ULL;
      pk.u = (pk.u & ~TAGM) | tg;
      const size_t off =
          ((size_t)l * (rsmask + 1) + (t & rsmask)) * BB * HH + (size_t)rb * HH + c0 + c4;
      // dual store, SAME address (round-15/20-proven): plain (dirty local L2)
      // + atomic write-through (MALL master / termination guarantee)
      *reinterpret_cast<ull*>(hbuf + off) = pk.u;
      __hip_atomic_store(reinterpret_cast<ull*>(hbuf + off), pk.u,
                         __ATOMIC_RELAXED, __HIP_MEMORY_SCOPE_AGENT);
    }
    if (l == NL - 1) {
      f32x4 o = {v[0], v[1], v[2], v[3]};
      __builtin_nontemporal_store(
          o, reinterpret_cast<f32x4*>(out + ((size_t)rb * LL + t) * HH + c0 + c4));
    }
    if (t == LL - 1) {
      f32x4 o = {v[0], v[1], v[2], v[3]};
      __builtin_nontemporal_store(
          o, reinterpret_cast<f32x4*>(out + (size_t)BB * LL * HH +
                                      ((size_t)l * BB + rb) * HH + c0 + c4));
    }

    // ---------- barrier 5: DRAIN-EARLY (vmcnt(0): h at L2/MALL NOW) ----------
    __syncthreads();
    // ---------- publish step t complete+drained, immediately ----------
    if (tid == 0)
      __hip_atomic_store(&pflag[l * TPL + tile], (unsigned)(t + 1), __ATOMIC_RELAXED,
                         __HIP_MEMORY_SCOPE_AGENT);
  }
#undef RED
}

extern "C" void kernel_launch(void* const* d_in, const int* in_sizes, int n_in,
                              void* d_out, int out_size, void* d_ws, size_t ws_size,
                              hipStream_t stream) {
  const float* x  = (const float*)d_in[0];
  const float* h0 = (const float*)d_in[1];
  const float* WI = (const float*)d_in[2];
  const float* BI = (const float*)d_in[3];
  const float* WH = (const float*)d_in[4];
  const float* BH = (const float*)d_in[5];
  float* out = (float*)d_out;

  // RS (slots per layer): prefer 512 = fully write-once h stream (no WAR).
  const size_t perSlot = (size_t)NL * BB * HH * sizeof(_Float16);  // 256 KB
  int rs = 512;
  while (rs > 8 && (size_t)rs * perSlot + 65536 > ws_size) rs >>= 1;
  int rshift = 0;
  while ((1 << rshift) < rs) ++rshift;

  _Float16* hbuf = (_Float16*)d_ws;
  unsigned* pflag = (unsigned*)((char*)d_ws + (size_t)rs * perSlot);

  const int smemBytes = 2 * 32 * SROW * (int)sizeof(_Float16);  // 132096 (RED aliased)
  static int attrSet = 0;
  if (!attrSet) {
    hipFuncSetAttribute(reinterpret_cast<const void*>(rnn_persist),
                        hipFuncAttributeMaxDynamicSharedMemorySize, smemBytes);
    attrSet = 1;
  }

  hipMemsetAsync(pflag, 0, (size_t)NL * TPL * sizeof(unsigned), stream);
  rnn_persist<<<128, 512, smemBytes, stream>>>(x, h0, WI, BI, WH, BH, out, hbuf,
                                               pflag, rs - 1, rshift);
}